// Round 7
// baseline (1039.726 us; speedup 1.0000x reference)
//
#include <hip/hip_runtime.h>
#include <hip/hip_cooperative_groups.h>

namespace cg = cooperative_groups;

#define N_NODES   100000
#define N_EDGES   1600000
#define N_GRAPHS  128
#define HIDDEN    128
#define N_CLASSES 10

#define BSH   8                   // bucket = 256 nodes
#define BSZ   256
#define NBUCK 391                 // ceil(100000/256)
#define NPAD  (NBUCK * BSZ)       // 100096
#define NBIN  512                 // histogram bins (>= NBUCK)
#define CAP   8192                // mean fill 4096, 2x headroom
#define PCH   2048                // edges per partition chunk
#define NCHUNK ((N_EDGES + PCH - 1) / PCH)   // 782
#define BT    256                 // threads per block

typedef unsigned int   uint;
typedef unsigned short ushort;
typedef unsigned char  uchar;

// ---- workspace byte offsets (all compile-time; info 16B-aligned) ----
#define OFF_BCUR1 0u
#define OFF_BCUR2 (OFF_BCUR1 + NBIN*4u)
#define OFF_POOL  (OFF_BCUR2 + NBIN*4u)
#define OFF_CNT   (OFF_POOL + (uint)N_GRAPHS*HIDDEN*4u)
#define OFF_CIN   (OFF_CNT + (uint)N_GRAPHS*4u)
#define OFF_COUT  (OFF_CIN + (uint)NPAD*4u)
#define OFF_AGGC  (OFF_COUT + (uint)NPAD*4u)
#define OFF_AGGA  (OFF_AGGC + (uint)NPAD*4u)
#define OFF_AGGB  (OFF_AGGA + (uint)NPAD*4u)
#define OFF_MN    (OFF_AGGB + (uint)NPAD*4u)
#define OFF_MX    (OFF_MN + (uint)NPAD*4u)
#define OFF_NDV   (OFF_MX + (uint)NPAD*4u)
#define OFF_U     (OFF_NDV + (uint)NPAD*4u)
#define OFF_V     (OFF_U + 129u*HIDDEN*4u)
#define OFF_INFO  (OFF_V + 129u*HIDDEN*4u)       // 3405312, %16 == 0
#define OFF_TMP1  (OFF_INFO + (uint)NPAD*16u)
#define OFF_TMP2  (OFF_TMP1 + (uint)NBUCK*CAP*4u)

struct SMemPart { uint hist[NBIN]; uint lcur[NBIN]; uint base[NBIN]; uint wtmp[4];
                  uint stag4[PCH]; ushort stagB[PCH]; };           // ~18.1 KB
struct SMemCnt  { uint lin[BSZ]; uint lout[BSZ]; };
struct SMemA1   { float agg[BSZ]; };
struct SMemInf  { float stu[128]; };
struct SMemA2   { float lA[BSZ]; float lB[BSZ]; uint lmn[BSZ]; uint lmx[BSZ]; };
struct SMemPool { float psl[4][HIDDEN]; float csl[4]; uint tfl[4]; int g0s; };
struct SMemUV   { float sts[128]; };
struct SMemFin  { float sWc[HIDDEN*N_CLASSES]; float sbc[N_CLASSES]; };
union  SMem     { SMemPart part; SMemCnt cnt; SMemA1 a1; SMemInf inf;
                  SMemA2 a2; SMemPool pool; SMemUV uv; SMemFin fin; };

// 512-bin alloc-scan, 2 bins/thread, 256 threads (contains uniform syncs)
__device__ __forceinline__ void scan_alloc(SMemPart& P, uint* bcur, int t) {
    uint v0 = P.hist[2*t], v1 = P.hist[2*t+1];
    uint s = v0 + v1, lane = (uint)(t & 63), incl = s;
    #pragma unroll
    for (int off = 1; off < 64; off <<= 1) {
        uint up = __shfl_up(incl, off, 64);
        if (lane >= (uint)off) incl += up;
    }
    if (lane == 63) P.wtmp[t >> 6] = incl;
    __syncthreads();
    uint wo = 0; int w = t >> 6;
    #pragma unroll
    for (int k = 0; k < 3; ++k) wo += (k < w) ? P.wtmp[k] : 0u;
    uint ex = incl + wo - s;
    P.lcur[2*t] = ex; P.lcur[2*t+1] = ex + v0;
    if (v0) { uint g = atomicAdd(&bcur[2*t],   v0); P.base[2*t]   = (uint)(2*t)*CAP   + g - ex; }
    if (v1) { uint g = atomicAdd(&bcur[2*t+1], v1); P.base[2*t+1] = (uint)(2*t+1)*CAP + g - (ex+v0); }
}

__global__ __launch_bounds__(BT)
void k_mega(const int* __restrict__ src, const int* __restrict__ dst,
            const int* __restrict__ graph_ids,
            const float* __restrict__ W1, const float* __restrict__ b1,
            const float* __restrict__ W2, const float* __restrict__ b2,
            const float* __restrict__ Wc, const float* __restrict__ bc,
            float* __restrict__ out, char* __restrict__ ws) {
    __shared__ SMem sm;
    cg::grid_group grid = cg::this_grid();
    int t = threadIdx.x;

    uint*   bcur1 = (uint*)  (ws + OFF_BCUR1);
    uint*   bcur2 = (uint*)  (ws + OFF_BCUR2);
    float*  poolA = (float*) (ws + OFF_POOL);
    float*  cntA  = (float*) (ws + OFF_CNT);
    uint*   cin   = (uint*)  (ws + OFF_CIN);
    uint*   coutA = (uint*)  (ws + OFF_COUT);
    float*  aggC  = (float*) (ws + OFF_AGGC);
    float*  aggA  = (float*) (ws + OFF_AGGA);
    float*  aggB  = (float*) (ws + OFF_AGGB);
    uint*   aggMn = (uint*)  (ws + OFF_MN);
    uint*   aggMx = (uint*)  (ws + OFF_MX);
    float*  ndv   = (float*) (ws + OFF_NDV);
    float*  U     = (float*) (ws + OFF_U);
    float*  V     = (float*) (ws + OFF_V);
    float4* info  = (float4*)(ws + OFF_INFO);
    uint*   tmp1  = (uint*)  (ws + OFF_TMP1);
    uchar*  tmp2  = (uchar*) (ws + OFF_TMP2);

    // ================= P0: zero accumulators + U/V segment table =============
    {
        uint* wsw = (uint*)ws;
        uint z1 = OFF_MN / 4u;                        // [0, MN) -> 0
        for (uint w = (uint)blockIdx.x*BT + t; w < z1; w += (uint)gridDim.x*BT) wsw[w] = 0u;
        uint m0 = OFF_MN / 4u, m1 = OFF_MX / 4u;      // [MN, MX) -> 255
        for (uint w = m0 + (uint)blockIdx.x*BT + t; w < m1; w += (uint)gridDim.x*BT) wsw[w] = 255u;
        uint x0 = OFF_MX / 4u, x1 = OFF_NDV / 4u;     // [MX, NDV) -> 0
        for (uint w = x0 + (uint)blockIdx.x*BT + t; w < x1; w += (uint)gridDim.x*BT) wsw[w] = 0u;

        for (int b = blockIdx.x; b < 129; b += gridDim.x) {   // U/V rows
            if (t < 128) {
                float w = W1[t], bb = b1[t];
                sm.uv.sts[t] = (w != 0.0f) ? (-bb / w) : 1e30f;
            }
            __syncthreads();
            for (int k = 2; k <= 128; k <<= 1) {
                for (int j = k >> 1; j > 0; j >>= 1) {
                    if (t < 128) {
                        int ixj = t ^ j;
                        if (ixj > t) {
                            float a = sm.uv.sts[t], bb = sm.uv.sts[ixj];
                            bool up = ((t & k) == 0);
                            if (up ? (a > bb) : (a < bb)) { sm.uv.sts[t] = bb; sm.uv.sts[ixj] = a; }
                        }
                    }
                    __syncthreads();
                }
            }
            if (t < 128) {
                int sg = b;
                float a_rep;
                if (sg == 0)        a_rep = sm.uv.sts[0]   - 1.0f;
                else if (sg == 128) a_rep = sm.uv.sts[127] + 1.0f;
                else                a_rep = 0.5f * (sm.uv.sts[sg-1] + sm.uv.sts[sg]);
                float u = 0.0f, vv = 0.0f;
                #pragma unroll 8
                for (int j = 0; j < 128; ++j) {
                    float w  = W1[j], bb = b1[j];
                    float w2 = W2[j * HIDDEN + t];
                    bool on  = (a_rep * w + bb > 0.0f);
                    u  += on ? w  * w2 : 0.0f;
                    vv += on ? bb * w2 : 0.0f;
                }
                U[sg * HIDDEN + t] = u;
                V[sg * HIDDEN + t] = vv;
            }
            __syncthreads();
        }
    }
    grid.sync();

    // ================= P1: partition into 256-node buckets ===================
    for (int u = blockIdx.x; u < NCHUNK; u += gridDim.x) {
        int e0 = u * PCH;
        int e1 = min(e0 + PCH, N_EDGES);
        int cntE = e1 - e0;
        int sv[8], dv[8];
        // phase 1: dst
        sm.part.hist[t] = 0; sm.part.hist[t + 256] = 0;
        __syncthreads();
        #pragma unroll
        for (int m = 0; m < 8; ++m) {
            int e = e0 + t + m * BT;
            if (e < e1) {
                sv[m] = src[e]; dv[m] = dst[e];
                atomicAdd(&sm.part.hist[dv[m] >> BSH], 1u);
            }
        }
        __syncthreads();
        scan_alloc(sm.part, bcur1, t);
        __syncthreads();
        #pragma unroll
        for (int m = 0; m < 8; ++m) {
            int e = e0 + t + m * BT;
            if (e < e1) {
                int d = dv[m], s = sv[m], b = d >> BSH;
                uint p = atomicAdd(&sm.part.lcur[b], 1u);
                sm.part.stag4[p] = ((uint)(d & (BSZ - 1)) << 17) | (uint)s;
                sm.part.stagB[p] = (ushort)b;
            }
        }
        __syncthreads();
        for (int i = t; i < cntE; i += BT) {
            uint b = sm.part.stagB[i];
            uint a = sm.part.base[b] + (uint)i;
            if (a < (b + 1u) * CAP) tmp1[a] = sm.part.stag4[i];
        }
        __syncthreads();
        // phase 2: src
        sm.part.hist[t] = 0; sm.part.hist[t + 256] = 0;
        __syncthreads();
        #pragma unroll
        for (int m = 0; m < 8; ++m) {
            int e = e0 + t + m * BT;
            if (e < e1) atomicAdd(&sm.part.hist[sv[m] >> BSH], 1u);
        }
        __syncthreads();
        scan_alloc(sm.part, bcur2, t);
        __syncthreads();
        #pragma unroll
        for (int m = 0; m < 8; ++m) {
            int e = e0 + t + m * BT;
            if (e < e1) {
                int s = sv[m];
                uint p = atomicAdd(&sm.part.lcur[s >> BSH], 1u);
                sm.part.stag4[p] = (uint)s;
            }
        }
        __syncthreads();
        for (int i = t; i < cntE; i += BT) {
            uint s = sm.part.stag4[i];
            uint b = s >> BSH;
            uint a = sm.part.base[b] + (uint)i;
            if (a < (b + 1u) * CAP) tmp2[a] = (uchar)(s & (BSZ - 1));
        }
        __syncthreads();
    }
    grid.sync();

    // ================= P2: degrees (bucket-quarter units, coalesced merge) ===
    for (int u = blockIdx.x; u < NBUCK * 4; u += gridDim.x) {
        int b = u >> 2, q = u & 3;
        sm.cnt.lin[t] = 0; sm.cnt.lout[t] = 0;
        __syncthreads();
        uint f1 = min(bcur1[b], (uint)CAP);
        uint lo = f1 * (uint)q / 4u, hi = f1 * (uint)(q + 1) / 4u;
        const uint* tp1 = tmp1 + (size_t)b * CAP;
        uint i = lo + t;
        for (; i + 3u*BT < hi; i += 4u*BT) {
            uint a0 = tp1[i], a1 = tp1[i+BT], a2 = tp1[i+2u*BT], a3 = tp1[i+3u*BT];
            atomicAdd(&sm.cnt.lin[a0 >> 17], 1u); atomicAdd(&sm.cnt.lin[a1 >> 17], 1u);
            atomicAdd(&sm.cnt.lin[a2 >> 17], 1u); atomicAdd(&sm.cnt.lin[a3 >> 17], 1u);
        }
        for (; i < hi; i += BT) atomicAdd(&sm.cnt.lin[tp1[i] >> 17], 1u);

        uint f2 = min(bcur2[b], (uint)CAP);
        const uchar* tp2 = tmp2 + (size_t)b * CAP;
        const uint* tp2w = (const uint*)tp2;          // CAP-aligned
        uint nw = f2 >> 2;
        uint wlo = nw * (uint)q / 4u, whi = nw * (uint)(q + 1) / 4u;
        for (i = wlo + t; i < whi; i += BT) {
            uint w4 = tp2w[i];
            atomicAdd(&sm.cnt.lout[w4 & 255u], 1u);
            atomicAdd(&sm.cnt.lout[(w4 >> 8) & 255u], 1u);
            atomicAdd(&sm.cnt.lout[(w4 >> 16) & 255u], 1u);
            atomicAdd(&sm.cnt.lout[(w4 >> 24) & 255u], 1u);
        }
        if (q == 3) for (i = (nw << 2) + t; i < f2; i += BT) atomicAdd(&sm.cnt.lout[tp2[i]], 1u);
        __syncthreads();
        int n = b * BSZ + t;
        if (sm.cnt.lin[t])  atomicAdd(&cin[n],   sm.cnt.lin[t]);
        if (sm.cnt.lout[t]) atomicAdd(&coutA[n], sm.cnt.lout[t]);
        __syncthreads();
    }
    grid.sync();

    // ================= P3: conv1 aggregation (hs0 on the fly) ================
    for (int u = blockIdx.x; u < NBUCK * 4; u += gridDim.x) {
        int b = u >> 2, q = u & 3;
        sm.a1.agg[t] = 0.0f;
        __syncthreads();
        uint f1 = min(bcur1[b], (uint)CAP);
        uint lo = f1 * (uint)q / 4u, hi = f1 * (uint)(q + 1) / 4u;
        const uint* tp1 = tmp1 + (size_t)b * CAP;
        uint i = lo + t;
        for (; i + 3u*BT < hi; i += 4u*BT) {
            uint e0 = tp1[i], e1 = tp1[i+BT], e2 = tp1[i+2u*BT], e3 = tp1[i+3u*BT];
            uint s0 = e0 & 0x1FFFFu, s1 = e1 & 0x1FFFFu, s2 = e2 & 0x1FFFFu, s3 = e3 & 0x1FFFFu;
            uint c0 = cin[s0], c1 = cin[s1], c2 = cin[s2], c3 = cin[s3];
            uint o0 = coutA[s0], o1 = coutA[s1], o2 = coutA[s2], o3 = coutA[s3];
            float h0 = (float)c0 * rsqrtf(fmaxf((float)o0, 1.0f));
            float h1 = (float)c1 * rsqrtf(fmaxf((float)o1, 1.0f));
            float h2 = (float)c2 * rsqrtf(fmaxf((float)o2, 1.0f));
            float h3 = (float)c3 * rsqrtf(fmaxf((float)o3, 1.0f));
            atomicAdd(&sm.a1.agg[e0 >> 17], h0); atomicAdd(&sm.a1.agg[e1 >> 17], h1);
            atomicAdd(&sm.a1.agg[e2 >> 17], h2); atomicAdd(&sm.a1.agg[e3 >> 17], h3);
        }
        for (; i < hi; i += BT) {
            uint e = tp1[i];
            uint s = e & 0x1FFFFu;
            float h = (float)cin[s] * rsqrtf(fmaxf((float)coutA[s], 1.0f));
            atomicAdd(&sm.a1.agg[e >> 17], h);
        }
        __syncthreads();
        if (sm.a1.agg[t] != 0.0f) atomicAdd(&aggC[b * BSZ + t], sm.a1.agg[t]);
        __syncthreads();
    }
    grid.sync();

    // ================= P4: node info (av, segment id, ns, nd) ================
    if (t < 128) {
        float w = W1[t], bb = b1[t];
        sm.inf.stu[t] = (w != 0.0f) ? (-bb / w) : 1e30f;
    }
    __syncthreads();
    for (int n = blockIdx.x * BT + t; n < NPAD; n += gridDim.x * BT) {
        uint ci = cin[n];
        float nd = rsqrtf(fmaxf((float)ci, 1.0f));
        float av = aggC[n] * nd;
        int sgp = 0;
        #pragma unroll 16
        for (int qq = 0; qq < 128; ++qq) sgp += (sm.inf.stu[qq] < av) ? 1 : 0;
        float nsv = rsqrtf(fmaxf((float)coutA[n], 1.0f));
        info[n] = make_float4(nsv * av, nsv, __int_as_float(sgp), nd);
        ndv[n]  = nd;
    }
    grid.sync();

    // ================= P5: conv2 aggregation =================================
    for (int u = blockIdx.x; u < NBUCK * 4; u += gridDim.x) {
        int b = u >> 2, q = u & 3;
        sm.a2.lA[t] = 0.0f; sm.a2.lB[t] = 0.0f; sm.a2.lmn[t] = 255u; sm.a2.lmx[t] = 0u;
        __syncthreads();
        uint f1 = min(bcur1[b], (uint)CAP);
        uint lo = f1 * (uint)q / 4u, hi = f1 * (uint)(q + 1) / 4u;
        const uint* tp1 = tmp1 + (size_t)b * CAP;
        uint i = lo + t;
        for (; i + 3u*BT < hi; i += 4u*BT) {
            uint e0 = tp1[i], e1 = tp1[i+BT], e2 = tp1[i+2u*BT], e3 = tp1[i+3u*BT];
            float4 n0 = info[e0 & 0x1FFFFu];
            float4 n1 = info[e1 & 0x1FFFFu];
            float4 n2 = info[e2 & 0x1FFFFu];
            float4 n3 = info[e3 & 0x1FFFFu];
            uint d0 = e0 >> 17, d1 = e1 >> 17, d2 = e2 >> 17, d3 = e3 >> 17;
            atomicAdd(&sm.a2.lA[d0], n0.x); atomicAdd(&sm.a2.lB[d0], n0.y);
            atomicAdd(&sm.a2.lA[d1], n1.x); atomicAdd(&sm.a2.lB[d1], n1.y);
            atomicAdd(&sm.a2.lA[d2], n2.x); atomicAdd(&sm.a2.lB[d2], n2.y);
            atomicAdd(&sm.a2.lA[d3], n3.x); atomicAdd(&sm.a2.lB[d3], n3.y);
            uint s0 = (uint)__float_as_int(n0.z), s1 = (uint)__float_as_int(n1.z);
            uint s2 = (uint)__float_as_int(n2.z), s3 = (uint)__float_as_int(n3.z);
            atomicMin(&sm.a2.lmn[d0], s0); atomicMax(&sm.a2.lmx[d0], s0);
            atomicMin(&sm.a2.lmn[d1], s1); atomicMax(&sm.a2.lmx[d1], s1);
            atomicMin(&sm.a2.lmn[d2], s2); atomicMax(&sm.a2.lmx[d2], s2);
            atomicMin(&sm.a2.lmn[d3], s3); atomicMax(&sm.a2.lmx[d3], s3);
        }
        for (; i < hi; i += BT) {
            uint e = tp1[i];
            uint dl = e >> 17;
            float4 nf = info[e & 0x1FFFFu];
            atomicAdd(&sm.a2.lA[dl], nf.x);
            atomicAdd(&sm.a2.lB[dl], nf.y);
            uint sg = (uint)__float_as_int(nf.z);
            atomicMin(&sm.a2.lmn[dl], sg);
            atomicMax(&sm.a2.lmx[dl], sg);
        }
        __syncthreads();
        if (sm.a2.lmn[t] <= sm.a2.lmx[t]) {     // touched
            int n = b * BSZ + t;
            atomicAdd(&aggA[n], sm.a2.lA[t]);
            atomicAdd(&aggB[n], sm.a2.lB[t]);
            atomicMin(&aggMn[n], sm.a2.lmn[t]);
            atomicMax(&aggMx[n], sm.a2.lmx[t]);
        }
        __syncthreads();
    }
    grid.sync();

    // ================= P6: rows + pooling (128 nodes/unit) ===================
    for (int u = blockIdx.x; u < NPAD / 128; u += gridDim.x) {
        int nb = u * 128;
        if (t < 4) { sm.pool.csl[t] = 0.0f; sm.pool.tfl[t] = 0u; }
        for (int s2 = t; s2 < 4 * HIDDEN; s2 += BT) ((float*)sm.pool.psl)[s2] = 0.0f;
        if (t == 0) sm.pool.g0s = graph_ids[nb < N_NODES ? nb : (N_NODES - 1)];
        __syncthreads();
        int g0 = sm.pool.g0s;
        int d = t & 127, j = t >> 7;
        float b2d = b2[d];
        int gcur = -1; float racc = 0.0f, cl = 0.0f;
        for (int r = j; r < 128; r += 2) {
            int n = nb + r;
            if (n >= N_NODES) break;
            uint mn = aggMn[n], mx = aggMx[n];
            float acc;
            if (mn >= mx) {                 // uniform segment (or no edges: A=B=0)
                uint sg = min(mn, 128u);
                acc = aggA[n] * U[sg * HIDDEN + d] + aggB[n] * V[sg * HIDDEN + d];
            } else {                        // mixed: exact rescan of bucket edges (rare)
                acc = 0.0f;
                int bb = n >> BSH;
                uint f1 = min(bcur1[bb], (uint)CAP);
                const uint* tp1b = tmp1 + (size_t)bb * CAP;
                uint dl = (uint)(n & (BSZ - 1));
                for (uint k = 0; k < f1; ++k) {
                    uint e = tp1b[k];
                    if ((e >> 17) == dl) {
                        float4 nf = info[e & 0x1FFFFu];
                        uint sg = (uint)__float_as_int(nf.z);
                        acc += nf.x * U[sg * HIDDEN + d] + nf.y * V[sg * HIDDEN + d];
                    }
                }
            }
            float row = fmaxf(ndv[n] * acc + b2d, 0.0f);
            int g = graph_ids[n];
            if (g != gcur) {
                if (gcur >= 0) {
                    int slot = gcur - g0;
                    if (slot >= 0 && slot < 4) {
                        atomicAdd(&sm.pool.psl[slot][d], racc);
                        if (d == 0) { atomicAdd(&sm.pool.csl[slot], cl); sm.pool.tfl[slot] = 1u; }
                    } else {
                        atomicAdd(&poolA[gcur * HIDDEN + d], racc);
                        if (d == 0) atomicAdd(&cntA[gcur], cl);
                    }
                }
                gcur = g; racc = 0.0f; cl = 0.0f;
            }
            racc += row; cl += 1.0f;
        }
        if (gcur >= 0) {
            int slot = gcur - g0;
            if (slot >= 0 && slot < 4) {
                atomicAdd(&sm.pool.psl[slot][d], racc);
                if (d == 0) { atomicAdd(&sm.pool.csl[slot], cl); sm.pool.tfl[slot] = 1u; }
            } else {
                atomicAdd(&poolA[gcur * HIDDEN + d], racc);
                if (d == 0) atomicAdd(&cntA[gcur], cl);
            }
        }
        __syncthreads();
        #pragma unroll
        for (int s2 = 0; s2 < 4; ++s2) {
            if (sm.pool.tfl[s2]) {
                if (t < 128) atomicAdd(&poolA[(g0 + s2) * HIDDEN + t], sm.pool.psl[s2][t]);
                if (t == 128) atomicAdd(&cntA[g0 + s2], sm.pool.csl[s2]);
            }
        }
        __syncthreads();
    }
    grid.sync();

    // ================= P7: classifier head (block 0) =========================
    if (blockIdx.x == 0) {
        for (int s2 = t; s2 < HIDDEN * N_CLASSES; s2 += BT) sm.fin.sWc[s2] = Wc[s2];
        if (t < N_CLASSES) sm.fin.sbc[t] = bc[t];
        __syncthreads();
        int g = t >> 1, half = t & 1;
        float a[N_CLASSES];
        #pragma unroll
        for (int c = 0; c < N_CLASSES; ++c) a[c] = 0.0f;
        for (int jj = half * 64; jj < half * 64 + 64; ++jj) {
            float p = poolA[g * HIDDEN + jj];
            #pragma unroll
            for (int c = 0; c < N_CLASSES; ++c) a[c] += p * sm.fin.sWc[jj * N_CLASSES + c];
        }
        #pragma unroll
        for (int c = 0; c < N_CLASSES; ++c) a[c] += __shfl_xor(a[c], 1);
        if (half == 0) {
            float inv = 1.0f / fmaxf(cntA[g], 1.0f);
            #pragma unroll
            for (int c = 0; c < N_CLASSES; ++c)
                out[g * N_CLASSES + c] = sm.fin.sbc[c] + a[c] * inv;
        }
    }
}

extern "C" void kernel_launch(void* const* d_in, const int* in_sizes, int n_in,
                              void* d_out, int out_size, void* d_ws, size_t ws_size,
                              hipStream_t stream) {
    const int*   src       = (const int*)d_in[0];
    const int*   dst       = (const int*)d_in[1];
    const int*   graph_ids = (const int*)d_in[2];
    const float* W1        = (const float*)d_in[3];
    const float* b1        = (const float*)d_in[4];
    const float* W2        = (const float*)d_in[5];
    const float* b2        = (const float*)d_in[6];
    const float* Wc        = (const float*)d_in[7];
    const float* bc        = (const float*)d_in[8];
    float* outp = (float*)d_out;
    char*  wsp  = (char*)d_ws;

    static int g_blocks = 0;
    if (g_blocks == 0) {
        hipDeviceProp_t prop{};
        int bpc = 0, nblk = 0;
        if (hipGetDeviceProperties(&prop, 0) == hipSuccess &&
            hipOccupancyMaxActiveBlocksPerMultiprocessor(
                &bpc, reinterpret_cast<const void*>(k_mega), BT, 0) == hipSuccess) {
            nblk = bpc * prop.multiProcessorCount;
        }
        if (nblk <= 0) nblk = 1024;
        if (nblk > NBUCK * 4) nblk = NBUCK * 4;     // 1564 = max parallel units
        g_blocks = nblk;
    }

    void* args[] = { (void*)&src, (void*)&dst, (void*)&graph_ids,
                     (void*)&W1, (void*)&b1, (void*)&W2, (void*)&b2,
                     (void*)&Wc, (void*)&bc, (void*)&outp, (void*)&wsp };
    hipLaunchCooperativeKernel(reinterpret_cast<const void*>(k_mega),
                               dim3(g_blocks), dim3(BT), args, 0, stream);
}

// Round 8
// 215.712 us; speedup vs baseline: 4.8200x; 4.8200x over previous
//
#include <hip/hip_runtime.h>

#define N_NODES   100000
#define N_EDGES   1600000
#define N_GRAPHS  128
#define HIDDEN    128
#define N_CLASSES 10

#define BSH   8                   // bucket = 256 nodes
#define BSZ   256
#define NBUCK 391                 // ceil(100000/256)
#define NPAD  (NBUCK * BSZ)       // 100096
#define NBIN  512                 // histogram bins (>= NBUCK), == PTH
#define CAP   8192                // mean fill 4096, 2x headroom
#define PCH   4096                // edges per partition block
#define PTH   512                 // partition threads
#define PIT   (PCH / PTH)         // 8

typedef unsigned int   uint;
typedef unsigned short ushort;

// ---- 512-wide exclusive scan: wave shfl scan + cross-wave fixup (2 syncs)
__device__ __forceinline__ uint scan_excl_512(uint v, int t, uint* wtmp) {
    uint lane = (uint)(t & 63);
    uint incl = v;
    #pragma unroll
    for (int off = 1; off < 64; off <<= 1) {
        uint up = __shfl_up(incl, off, 64);
        if (lane >= (uint)off) incl += up;
    }
    if (lane == 63) wtmp[t >> 6] = incl;
    __syncthreads();
    uint wo = 0;
    int w = t >> 6;
    #pragma unroll
    for (int k = 0; k < 7; ++k) wo += (k < w) ? wtmp[k] : 0u;
    __syncthreads();
    return incl + wo - v;
}

// -------- partition by dst ONLY (phase 2 deleted); outdeg via fused
//          fire-and-forget global atomics (1.6M scattered u32, LLC-resident).
__global__ __launch_bounds__(PTH)
void k_part(const int* __restrict__ src, const int* __restrict__ dst,
            uint* __restrict__ bcur1, uint* __restrict__ outdeg,
            uint* __restrict__ tmp1, int nE) {
    __shared__ uint   hist[NBIN], lcur[NBIN], base[NBIN];
    __shared__ uint   wtmp[8];
    __shared__ uint   stag4[PCH];        // 16 KB
    __shared__ ushort stagB[PCH];        // 8 KB
    int t = threadIdx.x;
    int e0 = blockIdx.x * PCH;
    int e1 = min(e0 + PCH, nE);
    int cntE = e1 - e0;

    int sv[PIT], dv[PIT];
    hist[t] = 0;                         // NBIN == PTH
    __syncthreads();
    #pragma unroll
    for (int m = 0; m < PIT; ++m) {
        int e = e0 + t + m * PTH;
        if (e < e1) {
            sv[m] = src[e]; dv[m] = dst[e];
            atomicAdd(&hist[dv[m] >> BSH], 1u);
            atomicAdd(&outdeg[sv[m]], 1u);      // fire-and-forget, overlaps
        }
    }
    __syncthreads();
    uint v = hist[t];
    uint excl = scan_excl_512(v, t, wtmp);
    lcur[t] = excl;
    if (v > 0) { uint g = atomicAdd(&bcur1[t], v); base[t] = (uint)t * CAP + g - excl; }
    __syncthreads();
    #pragma unroll
    for (int m = 0; m < PIT; ++m) {
        int e = e0 + t + m * PTH;
        if (e < e1) {
            int d = dv[m], s = sv[m];
            int b = d >> BSH;
            uint p = atomicAdd(&lcur[b], 1u);
            stag4[p] = ((uint)(d & (BSZ - 1)) << 17) | (uint)s;
            stagB[p] = (ushort)b;
        }
    }
    __syncthreads();
    for (int i = t; i < cntE; i += PTH) {
        uint b = stagB[i];
        uint a = base[b] + (uint)i;
        if (a < (b + 1u) * CAP) tmp1[a] = stag4[i];
    }
}

// ------- per bucket (391 x 1024): indeg count + scan + CSR scatter +
//         ns / hs0 / rsind.  rsind[n] = (csr_row_start << 10) | indeg
__global__ __launch_bounds__(1024)
void k_cnt_csr(const uint* __restrict__ bcur1, const uint* __restrict__ tmp1,
               const uint* __restrict__ outdeg,
               uint* __restrict__ rsind, float* __restrict__ ns,
               float* __restrict__ hs0, int* __restrict__ csr) {
    __shared__ uint cin[BSZ], lcur[BSZ];
    __shared__ uint wtmp[4];
    int b = blockIdx.x, t = threadIdx.x;
    if (t < BSZ) cin[t] = 0;
    __syncthreads();
    uint f1 = min(bcur1[b], (uint)CAP);
    const uint* tp1 = tmp1 + (size_t)b * CAP;
    uint i = t;
    for (; i + 3072u < f1; i += 4096u) {
        uint a0 = tp1[i], a1 = tp1[i + 1024], a2 = tp1[i + 2048], a3 = tp1[i + 3072];
        atomicAdd(&cin[a0 >> 17], 1u); atomicAdd(&cin[a1 >> 17], 1u);
        atomicAdd(&cin[a2 >> 17], 1u); atomicAdd(&cin[a3 >> 17], 1u);
    }
    for (; i < f1; i += 1024u) atomicAdd(&cin[tp1[i] >> 17], 1u);
    __syncthreads();
    // 256-wide exclusive scan (4 waves + fixup)
    uint v = 0, incl = 0;
    if (t < BSZ) {
        v = cin[t];
        incl = v;
        uint lane = (uint)(t & 63);
        #pragma unroll
        for (int off = 1; off < 64; off <<= 1) {
            uint up = __shfl_up(incl, off, 64);
            if (lane >= (uint)off) incl += up;
        }
        if (lane == 63) wtmp[t >> 6] = incl;
    }
    __syncthreads();
    if (t < BSZ) {
        uint wo = 0;
        int w = t >> 6;
        #pragma unroll
        for (int k = 0; k < 3; ++k) wo += (k < w) ? wtmp[k] : 0u;
        uint excl = incl + wo - v;
        lcur[t] = excl;
        int n = b * BSZ + t;
        if (n < N_NODES) {
            uint co = outdeg[n];                       // coalesced read
            float nsv = rsqrtf(fmaxf((float)co, 1.0f));
            ns[n]    = nsv;
            hs0[n]   = (float)v * nsv;                 // h0 = indeg; hs0 = h0*norm_src
            rsind[n] = (((uint)b * CAP + excl) << 10) | min(v, 1023u);
        }
    }
    __syncthreads();
    int* cb = csr + (size_t)b * CAP;
    for (uint j = t; j < f1; j += 1024u) {
        uint e = tp1[j];
        uint pos = atomicAdd(&lcur[e >> 17], 1u);
        cb[pos] = (int)(e & 0x1FFFFu);
    }
}

// ---- conv1: 2 threads/node CSR gather + node info (R0-verified, verbatim).
//      Blocks 0..128 sort breakpoints + emit U/V rows.
__global__ __launch_bounds__(256)
void k_conv1_info(const uint* __restrict__ rsind, const int* __restrict__ csr,
                  const float* __restrict__ hs0, const float* __restrict__ ns,
                  const float* __restrict__ W1, const float* __restrict__ b1,
                  const float* __restrict__ W2,
                  float* __restrict__ U, float* __restrict__ V,
                  float4* __restrict__ info, int nN) {
    __shared__ float stu[128];        // unsorted breakpoints
    __shared__ float sts[128];        // sorted (only blocks < 129)
    int t = threadIdx.x;
    if (t < 128) {
        float w = W1[t], bb = b1[t];
        stu[t] = (w != 0.0f) ? (-bb / w) : 1e30f;
    }
    __syncthreads();
    if (blockIdx.x < 129) {           // block-uniform branch: syncs are legal
        if (t < 128) sts[t] = stu[t];
        __syncthreads();
        for (int k = 2; k <= 128; k <<= 1) {
            for (int j = k >> 1; j > 0; j >>= 1) {
                if (t < 128) {
                    int ixj = t ^ j;
                    if (ixj > t) {
                        float a = sts[t], bb = sts[ixj];
                        bool up = ((t & k) == 0);
                        if (up ? (a > bb) : (a < bb)) { sts[t] = bb; sts[ixj] = a; }
                    }
                }
                __syncthreads();
            }
        }
        if (t < 128) {                // segment-table row, unconditional loads
            int sg = blockIdx.x;
            float a_rep;
            if (sg == 0)        a_rep = sts[0]   - 1.0f;
            else if (sg == 128) a_rep = sts[127] + 1.0f;
            else                a_rep = 0.5f * (sts[sg - 1] + sts[sg]);
            float u = 0.0f, vv = 0.0f;
            #pragma unroll 8
            for (int j = 0; j < 128; ++j) {
                float w  = W1[j], bb = b1[j];
                float w2 = W2[j * HIDDEN + t];          // always load -> pipelined
                bool on  = (a_rep * w + bb > 0.0f);
                u  += on ? w  * w2 : 0.0f;
                vv += on ? bb * w2 : 0.0f;
            }
            U[sg * HIDDEN + t] = u;
            V[sg * HIDDEN + t] = vv;
        }
    }
    // per-node info: 2 threads per node, unsorted count
    int node = blockIdx.x * 128 + (t >> 1);
    if (node >= nN) return;
    int j  = t & 1;
    uint rix = rsind[node];
    int r0 = (int)(rix >> 10);
    int c  = (int)(rix & 1023u);
    float a = 0.0f;
    #pragma unroll 4
    for (int k = j; k < c; k += 2) a += hs0[csr[r0 + k]];
    a += __shfl_xor(a, 1);
    float nd = rsqrtf(fmaxf((float)c, 1.0f));
    float av = a * nd;
    int sgp = 0;
    #pragma unroll
    for (int q = 0; q < 64; ++q) sgp += (stu[j * 64 + q] < av) ? 1 : 0;
    sgp += __shfl_xor(sgp, 1);
    if (j == 0) {
        float nsv = ns[node];
        info[node] = make_float4(nsv * av, nsv, __int_as_float(sgp), nd);
    }
}

// ---- conv2: 4 threads/node register gather (R0-verified, verbatim); then ALL
//      4 waves compute relu rows (16 nodes each) into LDS; wave 0 pools.
__global__ __launch_bounds__(256)
void k_conv2_pool(const uint* __restrict__ rsind, const int* __restrict__ csr,
                  const float4* __restrict__ info,
                  const float* __restrict__ U, const float* __restrict__ V,
                  const int* __restrict__ graph_ids, const float* __restrict__ b2,
                  float* __restrict__ pool, float* __restrict__ cnt, int nN) {
    __shared__ float sA[64], sB[64], sND[64];
    __shared__ int   sSg[64], sGr[64], sR[64], sC[64];
    __shared__ float sRes[64][HIDDEN];          // 32 KB relu'd rows
    int blockBase = blockIdx.x * 64;
    int t = threadIdx.x;
    int node = blockBase + (t >> 2);
    int j = t & 3;

    float A = 0.0f, B = 0.0f;
    int mn = 255, mx = 0;
    int r0 = 0, c = 0;
    if (node < nN) {
        uint rix = rsind[node];
        r0 = (int)(rix >> 10); c = (int)(rix & 1023u);
        #pragma unroll 4
        for (int k = j; k < c; k += 4) {
            float4 nf = info[csr[r0 + k]];
            int sg = __float_as_int(nf.z);
            A += nf.x; B += nf.y;
            mn = min(mn, sg); mx = max(mx, sg);
        }
    }
    A += __shfl_xor(A, 1); A += __shfl_xor(A, 2);
    B += __shfl_xor(B, 1); B += __shfl_xor(B, 2);
    mn = min(mn, __shfl_xor(mn, 1)); mn = min(mn, __shfl_xor(mn, 2));
    mx = max(mx, __shfl_xor(mx, 1)); mx = max(mx, __shfl_xor(mx, 2));
    if (node < nN && j == 0) {
        int i = t >> 2;
        sA[i] = A; sB[i] = B;
        sSg[i] = (mn << 8) | mx;
        sR[i] = r0; sC[i] = c;
        sND[i] = info[node].w;
        sGr[i] = graph_ids[node];
    }
    __syncthreads();

    // phase 2a: all 4 waves compute relu rows (16 nodes each) -> LDS
    int w = t >> 6, lane = t & 63;
    float bb0 = b2[lane], bb1 = b2[64 + lane];
    for (int i = w * 16; i < w * 16 + 16; ++i) {
        int n = blockBase + i;
        if (n >= nN) break;
        int pk = sSg[i], smn = pk >> 8, smx = pk & 255;
        float acc0, acc1;
        if (smn >= smx) {                      // uniform segment (or no edges)
            int sg = min(smn, 128);
            float Av = sA[i], Bv = sB[i];
            const float* Ur = U + sg * HIDDEN;
            const float* Vr = V + sg * HIDDEN;
            acc0 = Av * Ur[lane]      + Bv * Vr[lane];
            acc1 = Av * Ur[64 + lane] + Bv * Vr[64 + lane];
        } else {                               // mixed: exact per-node rescan (rare)
            acc0 = 0.0f; acc1 = 0.0f;
            int rr = sR[i], cc = sC[i];
            for (int k = 0; k < cc; ++k) {
                float4 nf = info[csr[rr + k]];
                int sg = __float_as_int(nf.z);
                const float* Ur = U + sg * HIDDEN;
                const float* Vr = V + sg * HIDDEN;
                acc0 += nf.x * Ur[lane]      + nf.y * Vr[lane];
                acc1 += nf.x * Ur[64 + lane] + nf.y * Vr[64 + lane];
            }
        }
        float nd = sND[i];
        sRes[i][lane]      = fmaxf(nd * acc0 + bb0, 0.0f);
        sRes[i][64 + lane] = fmaxf(nd * acc1 + bb1, 0.0f);
    }
    __syncthreads();

    // phase 2b: wave 0 pools from LDS (sorted graph_ids -> few flushes)
    if (t >= 64) return;
    int lane0 = t;
    int gcur = -1;
    float racc0 = 0.0f, racc1 = 0.0f, cl = 0.0f;
    for (int i = 0; i < 64; ++i) {
        int n = blockBase + i;
        if (n >= nN) break;
        float r0v = sRes[i][lane0];
        float r1v = sRes[i][64 + lane0];
        int g = sGr[i];
        if (g != gcur) {
            if (gcur >= 0) {
                atomicAdd(&pool[gcur * HIDDEN + lane0],      racc0);
                atomicAdd(&pool[gcur * HIDDEN + 64 + lane0], racc1);
                if (lane0 == 0) atomicAdd(&cnt[gcur], cl);
            }
            gcur = g; racc0 = 0.0f; racc1 = 0.0f; cl = 0.0f;
        }
        racc0 += r0v; racc1 += r1v; cl += 1.0f;
    }
    if (gcur >= 0) {
        atomicAdd(&pool[gcur * HIDDEN + lane0],      racc0);
        atomicAdd(&pool[gcur * HIDDEN + 64 + lane0], racc1);
        if (lane0 == 0) atomicAdd(&cnt[gcur], cl);
    }
}

// ----------------------------------------------- classifier head (tiny)
__global__ void k_final(const float* __restrict__ pool, const float* __restrict__ cnt,
                        const float* __restrict__ Wc, const float* __restrict__ bc,
                        float* __restrict__ out) {
    int t = blockIdx.x * blockDim.x + threadIdx.x;
    if (t >= N_GRAPHS * N_CLASSES) return;
    int g = t / N_CLASSES, c = t % N_CLASSES;
    float inv = 1.0f / fmaxf(cnt[g], 1.0f);
    float acc = bc[c];
    for (int j = 0; j < HIDDEN; ++j)
        acc += pool[g * HIDDEN + j] * inv * Wc[j * N_CLASSES + c];
    out[t] = acc;
}

extern "C" void kernel_launch(void* const* d_in, const int* in_sizes, int n_in,
                              void* d_out, int out_size, void* d_ws, size_t ws_size,
                              hipStream_t stream) {
    const int*   src       = (const int*)d_in[0];
    const int*   dst       = (const int*)d_in[1];
    const int*   graph_ids = (const int*)d_in[2];
    const float* W1        = (const float*)d_in[3];
    const float* b1        = (const float*)d_in[4];
    const float* W2        = (const float*)d_in[5];
    const float* b2        = (const float*)d_in[6];
    const float* Wc        = (const float*)d_in[7];
    const float* bc        = (const float*)d_in[8];
    float* out = (float*)d_out;

    char* ws = (char*)d_ws;
    size_t off = 0;
    auto alloc = [&](size_t elems) { void* p = ws + off; off += elems * 4; return p; };

    // --- zeroed region (single ~470KB memset) ---
    uint*  bcur1  = (uint*) alloc(NBIN);                    // 2 KB
    uint*  outdeg = (uint*) alloc(NPAD);                    // 400 KB
    float* pool   = (float*)alloc(N_GRAPHS * HIDDEN);       // 64 KB
    float* cnt    = (float*)alloc(N_GRAPHS);                // 512 B
    size_t zero_bytes = off;                                // 468,480 B (%16==0)
    // --- non-zeroed ---
    float4* info  = (float4*)alloc((size_t)NPAD * 4);       // 1.6 MB (16B-aligned)
    uint*   tmp1  = (uint*)  alloc((size_t)NBUCK * CAP);    // 12.8 MB
    int*    csr   = (int*)   alloc((size_t)NBUCK * CAP);    // 12.8 MB
    uint*   rsind = (uint*)  alloc(NPAD);
    float*  nsA   = (float*) alloc(NPAD);
    float*  hs0   = (float*) alloc(NPAD);
    float*  U     = (float*) alloc(129 * HIDDEN);
    float*  V     = (float*) alloc(129 * HIDDEN);

    hipMemsetAsync(d_ws, 0, zero_bytes, stream);

    int pblocks  = (N_EDGES + PCH - 1) / PCH;    // 391
    int c1blocks = (N_NODES + 127) / 128;        // 782
    int c2blocks = (N_NODES + 63) / 64;          // 1563

    k_part      <<<pblocks, PTH, 0, stream>>>(src, dst, bcur1, outdeg, tmp1, N_EDGES);
    k_cnt_csr   <<<NBUCK, 1024, 0, stream>>>(bcur1, tmp1, outdeg, rsind, nsA, hs0, csr);
    k_conv1_info<<<c1blocks, 256, 0, stream>>>(rsind, csr, hs0, nsA, W1, b1, W2, U, V, info, N_NODES);
    k_conv2_pool<<<c2blocks, 256, 0, stream>>>(rsind, csr, info, U, V, graph_ids, b2, pool, cnt, N_NODES);
    k_final     <<<(N_GRAPHS * N_CLASSES + 255) / 256, 256, 0, stream>>>(pool, cnt, Wc, bc, out);
}